// Round 1
// baseline (419.325 us; speedup 1.0000x reference)
//
#include <hip/hip_runtime.h>
#include <hip/hip_bf16.h>
#include <math.h>

#define L2E 1.44269504088896340736f

using f32x4  = __attribute__((ext_vector_type(4))) float;
using bf16x8 = __attribute__((ext_vector_type(8))) short;

static __device__ __forceinline__ float b2f(unsigned short u) {
  union { unsigned u; float f; } v; v.u = ((unsigned)u) << 16; return v.f;
}
static __device__ __forceinline__ unsigned short f2b(float f) {
  union { float f; unsigned u; } v; v.f = f;
  unsigned r = (v.u + 0x7FFFu + ((v.u >> 16) & 1u)) >> 16;
  return (unsigned short)r;
}

// ---------------- fp32 -> bf16 convert (float4 vectorized) ----------------
__global__ void cvt_kernel(const float* __restrict__ src,
                           unsigned short* __restrict__ dst, int n4) {
  int i = blockIdx.x * blockDim.x + threadIdx.x;
  int stride = gridDim.x * blockDim.x;
  for (; i < n4; i += stride) {
    float4 v = ((const float4*)src)[i];
    ushort4 o;
    o.x = f2b(v.x); o.y = f2b(v.y); o.z = f2b(v.z); o.w = f2b(v.w);
    ((ushort4*)dst)[i] = o;
  }
}

// ---------------- RoPE cos/sin table: tab[s*32+j] = {cos,sin}(pos[s]*f_j) ----
__global__ void rope_table_kernel(const int* __restrict__ pos,
                                  float2* __restrict__ tab) {
  int t = blockIdx.x * blockDim.x + threadIdx.x;   // 0..65535
  int s = t >> 5, j = t & 31;
  double p = (double)pos[s];
  double freq = pow(10000.0, -(double)(2 * j) / 64.0);
  double ang = p * freq;
  tab[t] = make_float2((float)cos(ang), (float)sin(ang));
}

// ---------------- NT GEMM: C[M,N] = A[M,K] * B[N,K]^T (bf16 in, OUT out) ----
template <typename OUT>
__global__ __launch_bounds__(256) void gemm_nt(const unsigned short* __restrict__ A,
                                               const unsigned short* __restrict__ B,
                                               OUT* __restrict__ C,
                                               int M, int N, int K) {
  __shared__ unsigned short As[128 * 64];
  __shared__ unsigned short Bs[128 * 64];
  const int t = threadIdx.x;
  const int lane = t & 63;
  const int row_l = lane & 15;
  const int grp = lane >> 4;
  const int wave = t >> 6;
  const int wm = (wave >> 1) * 64;
  const int wn = (wave & 1) * 64;
  const int m0 = blockIdx.y * 128;
  const int n0 = blockIdx.x * 128;

  f32x4 acc[4][4];
#pragma unroll
  for (int i = 0; i < 4; ++i)
#pragma unroll
    for (int j = 0; j < 4; ++j) acc[i][j] = (f32x4){0.f, 0.f, 0.f, 0.f};

  const int srow = t >> 3;        // 0..31
  const int scolb = (t & 7) * 16; // byte within 128B row
  const size_t lda = (size_t)K * 2;
  const char* Ab = (const char*)A + (size_t)m0 * lda + scolb;
  const char* Bb = (const char*)B + (size_t)n0 * lda + scolb;

  for (int k0 = 0; k0 < K; k0 += 64) {
#pragma unroll
    for (int it = 0; it < 4; ++it) {
      int row = it * 32 + srow;
      const char* ga = Ab + (size_t)row * lda + (size_t)k0 * 2;
      const char* gb = Bb + (size_t)row * lda + (size_t)k0 * 2;
      __builtin_amdgcn_global_load_lds(
          (const __attribute__((address_space(1))) unsigned*)ga,
          (__attribute__((address_space(3))) unsigned*)((char*)As + it * 4096 + t * 16),
          16, 0, 0);
      __builtin_amdgcn_global_load_lds(
          (const __attribute__((address_space(1))) unsigned*)gb,
          (__attribute__((address_space(3))) unsigned*)((char*)Bs + it * 4096 + t * 16),
          16, 0, 0);
    }
    __syncthreads();
#pragma unroll
    for (int kk = 0; kk < 2; ++kk) {
      bf16x8 a[4], b[4];
#pragma unroll
      for (int i = 0; i < 4; ++i)
        a[i] = *(const bf16x8*)&As[(wm + 16 * i + row_l) * 64 + kk * 32 + grp * 8];
#pragma unroll
      for (int j = 0; j < 4; ++j)
        b[j] = *(const bf16x8*)&Bs[(wn + 16 * j + row_l) * 64 + kk * 32 + grp * 8];
#pragma unroll
      for (int i = 0; i < 4; ++i)
#pragma unroll
        for (int j = 0; j < 4; ++j)
          acc[i][j] = __builtin_amdgcn_mfma_f32_16x16x32_bf16(a[i], b[j], acc[i][j], 0, 0, 0);
    }
    __syncthreads();
  }
#pragma unroll
  for (int i = 0; i < 4; ++i)
#pragma unroll
    for (int j = 0; j < 4; ++j)
#pragma unroll
      for (int r = 0; r < 4; ++r) {
        int rowg = m0 + wm + 16 * i + grp * 4 + r;
        int colg = n0 + wn + 16 * j + row_l;
        float v = acc[i][j][r];
        if constexpr (sizeof(OUT) == 2) {
          C[(size_t)rowg * N + colg] = (OUT)f2b(v);
        } else {
          C[(size_t)rowg * N + colg] = v;
        }
      }
}

// ---------------- split qkv + RoPE(Q,K) + V transpose ----------------
// qkv: [8192, 2304] bf16.  Q,K: [B*H, S, 64] bf16 (Q pre-scaled 1/8).
// Vt: [B*H, 64, S] bf16 (transposed for PV B-operand).
__global__ __launch_bounds__(256) void split_rope_kernel(
    const unsigned short* __restrict__ qkv, const float2* __restrict__ tab,
    unsigned short* __restrict__ Qo, unsigned short* __restrict__ Ko,
    unsigned short* __restrict__ Vt) {
  int idx = blockIdx.x * 256 + threadIdx.x;  // (m, h, d2): 8192*12*32
  int d2 = idx & 31;
  int h = (idx >> 5) % 12;
  int m = idx / 384;
  int b = m >> 11, s = m & 2047;
  const unsigned short* rowp = qkv + (size_t)m * 2304;
  int c0 = h * 64 + 2 * d2;
  float qe = b2f(rowp[c0]),        qo = b2f(rowp[c0 + 1]);
  float ke = b2f(rowp[768 + c0]),  ko = b2f(rowp[768 + c0 + 1]);
  float ve = b2f(rowp[1536 + c0]), vo = b2f(rowp[1536 + c0 + 1]);
  float2 cs = tab[s * 32 + d2];
  float c = cs.x, sn = cs.y;
  float qre = (qe * c - qo * sn) * 0.125f;
  float qro = (qe * sn + qo * c) * 0.125f;
  float kre = ke * c - ko * sn;
  float kro = ke * sn + ko * c;
  size_t bh = (size_t)(b * 12 + h);
  size_t qoff = (bh * 2048 + s) * 64 + 2 * d2;
  ushort2 qv; qv.x = f2b(qre); qv.y = f2b(qro);
  *(ushort2*)&Qo[qoff] = qv;
  ushort2 kv; kv.x = f2b(kre); kv.y = f2b(kro);
  *(ushort2*)&Ko[qoff] = kv;
  Vt[(bh * 64 + 2 * d2) * 2048 + s]     = f2b(ve);
  Vt[(bh * 64 + 2 * d2 + 1) * 2048 + s] = f2b(vo);
}

// ---------------- causal flash attention ----------------
// grid (48, 32): x = b*12+h, y = q-tile (64 rows). 4 waves, 16 q-rows each.
__global__ __launch_bounds__(256) void attn_kernel(
    const unsigned short* __restrict__ Q, const unsigned short* __restrict__ Kc,
    const unsigned short* __restrict__ Vt, unsigned short* __restrict__ Ao) {
  __shared__ unsigned short Pl[4][16 * 72];  // per-wave P tile, padded to 72
  const int lane = threadIdx.x & 63;
  const int wave = threadIdx.x >> 6;
  const int row_l = lane & 15;
  const int grp = lane >> 4;
  const int bh = blockIdx.x;
  const int qt = blockIdx.y;
  const int q0 = qt * 64 + wave * 16;
  const size_t base = (size_t)bh * 2048 * 64;

  bf16x8 aq[2];
#pragma unroll
  for (int kk = 0; kk < 2; ++kk)
    aq[kk] = *(const bf16x8*)&Q[base + (size_t)(q0 + row_l) * 64 + kk * 32 + grp * 8];

  f32x4 o[4];
#pragma unroll
  for (int c2 = 0; c2 < 4; ++c2) o[c2] = (f32x4){0.f, 0.f, 0.f, 0.f};
  float mrow[4] = {-1e30f, -1e30f, -1e30f, -1e30f};
  float lrow[4] = {0.f, 0.f, 0.f, 0.f};
  unsigned short* Pw = Pl[wave];

  for (int kt = 0; kt <= qt; ++kt) {
    const int k0 = kt * 64;
    f32x4 sc[4];
#pragma unroll
    for (int c = 0; c < 4; ++c) sc[c] = (f32x4){0.f, 0.f, 0.f, 0.f};
#pragma unroll
    for (int c = 0; c < 4; ++c) {
      const unsigned short* kp = &Kc[base + (size_t)(k0 + c * 16 + row_l) * 64 + grp * 8];
      bf16x8 b0 = *(const bf16x8*)kp;
      bf16x8 b1 = *(const bf16x8*)(kp + 32);
      sc[c] = __builtin_amdgcn_mfma_f32_16x16x32_bf16(aq[0], b0, sc[c], 0, 0, 0);
      sc[c] = __builtin_amdgcn_mfma_f32_16x16x32_bf16(aq[1], b1, sc[c], 0, 0, 0);
    }
    if (kt == qt) {  // diagonal tile: causal mask
#pragma unroll
      for (int c = 0; c < 4; ++c) {
        int key = k0 + c * 16 + row_l;
#pragma unroll
        for (int r = 0; r < 4; ++r)
          if (key > q0 + grp * 4 + r) sc[c][r] = -1e30f;
      }
    }
    float tmax[4];
#pragma unroll
    for (int r = 0; r < 4; ++r) {
      float v = fmaxf(fmaxf(sc[0][r], sc[1][r]), fmaxf(sc[2][r], sc[3][r]));
      v = fmaxf(v, __shfl_xor(v, 1, 64));
      v = fmaxf(v, __shfl_xor(v, 2, 64));
      v = fmaxf(v, __shfl_xor(v, 4, 64));
      v = fmaxf(v, __shfl_xor(v, 8, 64));
      tmax[r] = v;
    }
    float al[4], rs[4];
#pragma unroll
    for (int r = 0; r < 4; ++r) {
      float nm = fmaxf(mrow[r], tmax[r]);
      al[r] = exp2f((mrow[r] - nm) * L2E);
      mrow[r] = nm;
      rs[r] = 0.f;
    }
#pragma unroll
    for (int c = 0; c < 4; ++c)
#pragma unroll
      for (int r = 0; r < 4; ++r) {
        float p = exp2f((sc[c][r] - mrow[r]) * L2E);
        sc[c][r] = p;
        rs[r] += p;
      }
#pragma unroll
    for (int r = 0; r < 4; ++r) {
      float v = rs[r];
      v += __shfl_xor(v, 1, 64);
      v += __shfl_xor(v, 2, 64);
      v += __shfl_xor(v, 4, 64);
      v += __shfl_xor(v, 8, 64);
      lrow[r] = lrow[r] * al[r] + v;
    }
#pragma unroll
    for (int c2 = 0; c2 < 4; ++c2)
#pragma unroll
      for (int r = 0; r < 4; ++r) o[c2][r] *= al[r];
    // P (bf16) -> LDS, then reload as MFMA A-fragments
#pragma unroll
    for (int c = 0; c < 4; ++c)
#pragma unroll
      for (int r = 0; r < 4; ++r)
        Pw[(grp * 4 + r) * 72 + c * 16 + row_l] = f2b(sc[c][r]);
    bf16x8 pa[2];
#pragma unroll
    for (int kk = 0; kk < 2; ++kk)
      pa[kk] = *(const bf16x8*)&Pw[row_l * 72 + kk * 32 + grp * 8];
#pragma unroll
    for (int c2 = 0; c2 < 4; ++c2) {
      const unsigned short* vp = &Vt[((size_t)bh * 64 + c2 * 16 + row_l) * 2048 + k0 + grp * 8];
      bf16x8 v0 = *(const bf16x8*)vp;
      bf16x8 v1 = *(const bf16x8*)(vp + 32);
      o[c2] = __builtin_amdgcn_mfma_f32_16x16x32_bf16(pa[0], v0, o[c2], 0, 0, 0);
      o[c2] = __builtin_amdgcn_mfma_f32_16x16x32_bf16(pa[1], v1, o[c2], 0, 0, 0);
    }
  }
  const int b = bh / 12, h = bh - b * 12;
#pragma unroll
  for (int r = 0; r < 4; ++r) {
    float inv = 1.0f / lrow[r];
    size_t orow = ((size_t)b * 2048 + q0 + grp * 4 + r) * 768 + h * 64;
#pragma unroll
    for (int c2 = 0; c2 < 4; ++c2)
      Ao[orow + c2 * 16 + row_l] = f2b(o[c2][r] * inv);
  }
}

extern "C" void kernel_launch(void* const* d_in, const int* in_sizes, int n_in,
                              void* d_out, int out_size, void* d_ws, size_t ws_size,
                              hipStream_t stream) {
  const float* x  = (const float*)d_in[0];
  const float* wq = (const float*)d_in[1];
  const float* wk = (const float*)d_in[2];
  const float* wv = (const float*)d_in[3];
  const float* wo = (const float*)d_in[4];
  const int* tpos = (const int*)d_in[5];
  float* out = (float*)d_out;

  char* ws = (char*)d_ws;
  // workspace layout (bytes)
  unsigned short* xb   = (unsigned short*)(ws + 0);           // 12,582,912 (reused as attn_out)
  unsigned short* wqkv = (unsigned short*)(ws + 12582912);    //  3,538,944
  unsigned short* wob  = (unsigned short*)(ws + 16121856);    //  1,179,648
  float2*         tab  = (float2*)(ws + 17301504);            //    524,288
  unsigned short* qkv  = (unsigned short*)(ws + 17825792);    // 37,748,736
  unsigned short* Qb   = (unsigned short*)(ws + 55574528);    // 12,582,912
  unsigned short* Kb   = (unsigned short*)(ws + 68157440);    // 12,582,912
  unsigned short* Vtb  = (unsigned short*)(ws + 80740352);    // 12,582,912
  unsigned short* aout = xb;  // alias: x_bf16 is dead after GEMM1

  // 1. converts
  cvt_kernel<<<2048, 256, 0, stream>>>(x, xb, 8192 * 768 / 4);
  cvt_kernel<<<576, 256, 0, stream>>>(wq, wqkv, 768 * 768 / 4);
  cvt_kernel<<<576, 256, 0, stream>>>(wk, wqkv + 589824, 768 * 768 / 4);
  cvt_kernel<<<576, 256, 0, stream>>>(wv, wqkv + 1179648, 768 * 768 / 4);
  cvt_kernel<<<576, 256, 0, stream>>>(wo, wob, 768 * 768 / 4);
  // 2. rope table
  rope_table_kernel<<<256, 256, 0, stream>>>(tpos, tab);
  // 3. qkv = x @ w_qkv^T   (M=8192, N=2304, K=768)
  gemm_nt<unsigned short><<<dim3(18, 64), 256, 0, stream>>>(xb, wqkv, qkv, 8192, 2304, 768);
  // 4. split + rope + V-transpose
  split_rope_kernel<<<12288, 256, 0, stream>>>(qkv, tab, Qb, Kb, Vtb);
  // 5. causal flash attention
  attn_kernel<<<dim3(48, 32), 256, 0, stream>>>(Qb, Kb, Vtb, aout);
  // 6. out = attn @ w_o^T  (M=8192, N=768, K=768), fp32 out
  gemm_nt<float><<<dim3(6, 64), 256, 0, stream>>>(aout, wob, out, 8192, 768, 768);
}

// Round 3
// 318.319 us; speedup vs baseline: 1.3173x; 1.3173x over previous
//
#include <hip/hip_runtime.h>
#include <hip/hip_bf16.h>
#include <math.h>

#define L2E 1.44269504088896340736f

using f32x4  = __attribute__((ext_vector_type(4))) float;
using f32x16 = __attribute__((ext_vector_type(16))) float;
using bf16x8 = __attribute__((ext_vector_type(8))) short;

static __device__ __forceinline__ float b2f(unsigned short u) {
  union { unsigned u; float f; } v; v.u = ((unsigned)u) << 16; return v.f;
}
static __device__ __forceinline__ unsigned short f2b(float f) {
  union { float f; unsigned u; } v; v.f = f;
  unsigned r = (v.u + 0x7FFFu + ((v.u >> 16) & 1u)) >> 16;
  return (unsigned short)r;
}
// pack two f32 -> one u32 of 2 bf16 (lo = a, hi = b), RNE
static __device__ __forceinline__ unsigned cvtpk(float a, float b) {
  unsigned r;
  asm("v_cvt_pk_bf16_f32 %0, %1, %2" : "=v"(r) : "v"(a), "v"(b));
  return r;
}
// swap halves: a' = {a.lanes0-31, b.lanes0-31}, b' = {a.lanes32-63, b.lanes32-63}
static __device__ __forceinline__ void plswap(unsigned& a, unsigned& b) {
#if __has_builtin(__builtin_amdgcn_permlane32_swap)
  typedef unsigned u32x2 __attribute__((ext_vector_type(2)));
  u32x2 r = __builtin_amdgcn_permlane32_swap(a, b, false, false);
  a = r[0]; b = r[1];
#else
  unsigned as = (unsigned)__shfl_xor((int)a, 32, 64);
  unsigned bs = (unsigned)__shfl_xor((int)b, 32, 64);
  bool lo = (threadIdx.x & 32) == 0;
  unsigned na = lo ? a : bs;
  unsigned nb = lo ? as : b;
  a = na; b = nb;
#endif
}

// ---------------- fp32 -> bf16 convert (float4 vectorized) ----------------
__global__ void cvt_kernel(const float* __restrict__ src,
                           unsigned short* __restrict__ dst, int n4) {
  int i = blockIdx.x * blockDim.x + threadIdx.x;
  int stride = gridDim.x * blockDim.x;
  for (; i < n4; i += stride) {
    float4 v = ((const float4*)src)[i];
    ushort4 o;
    o.x = f2b(v.x); o.y = f2b(v.y); o.z = f2b(v.z); o.w = f2b(v.w);
    ((ushort4*)dst)[i] = o;
  }
}

// ---------------- RoPE cos/sin table ----------------
__global__ void rope_table_kernel(const int* __restrict__ pos,
                                  float2* __restrict__ tab) {
  int t = blockIdx.x * blockDim.x + threadIdx.x;   // 0..65535
  int s = t >> 5, j = t & 31;
  double p = (double)pos[s];
  double freq = pow(10000.0, -(double)(2 * j) / 64.0);
  double ang = p * freq;
  tab[t] = make_float2((float)cos(ang), (float)sin(ang));
}

// ---------------- NT GEMM: C[M,N] = A[M,K] * B[N,K]^T ----------------
template <typename OUT>
__global__ __launch_bounds__(256) void gemm_nt(const unsigned short* __restrict__ A,
                                               const unsigned short* __restrict__ B,
                                               OUT* __restrict__ C,
                                               int M, int N, int K) {
  __shared__ unsigned short As[128 * 64];
  __shared__ unsigned short Bs[128 * 64];
  const int t = threadIdx.x;
  const int lane = t & 63;
  const int row_l = lane & 15;
  const int grp = lane >> 4;
  const int wave = t >> 6;
  const int wm = (wave >> 1) * 64;
  const int wn = (wave & 1) * 64;
  const int m0 = blockIdx.y * 128;
  const int n0 = blockIdx.x * 128;

  f32x4 acc[4][4];
#pragma unroll
  for (int i = 0; i < 4; ++i)
#pragma unroll
    for (int j = 0; j < 4; ++j) acc[i][j] = (f32x4){0.f, 0.f, 0.f, 0.f};

  const int srow = t >> 3;
  const int scolb = (t & 7) * 16;
  const size_t lda = (size_t)K * 2;
  const char* Ab = (const char*)A + (size_t)m0 * lda + scolb;
  const char* Bb = (const char*)B + (size_t)n0 * lda + scolb;

  for (int k0 = 0; k0 < K; k0 += 64) {
#pragma unroll
    for (int it = 0; it < 4; ++it) {
      int row = it * 32 + srow;
      const char* ga = Ab + (size_t)row * lda + (size_t)k0 * 2;
      const char* gb = Bb + (size_t)row * lda + (size_t)k0 * 2;
      __builtin_amdgcn_global_load_lds(
          (const __attribute__((address_space(1))) unsigned*)ga,
          (__attribute__((address_space(3))) unsigned*)((char*)As + it * 4096 + t * 16),
          16, 0, 0);
      __builtin_amdgcn_global_load_lds(
          (const __attribute__((address_space(1))) unsigned*)gb,
          (__attribute__((address_space(3))) unsigned*)((char*)Bs + it * 4096 + t * 16),
          16, 0, 0);
    }
    __syncthreads();
#pragma unroll
    for (int kk = 0; kk < 2; ++kk) {
      bf16x8 a[4], b[4];
#pragma unroll
      for (int i = 0; i < 4; ++i)
        a[i] = *(const bf16x8*)&As[(wm + 16 * i + row_l) * 64 + kk * 32 + grp * 8];
#pragma unroll
      for (int j = 0; j < 4; ++j)
        b[j] = *(const bf16x8*)&Bs[(wn + 16 * j + row_l) * 64 + kk * 32 + grp * 8];
#pragma unroll
      for (int i = 0; i < 4; ++i)
#pragma unroll
        for (int j = 0; j < 4; ++j)
          acc[i][j] = __builtin_amdgcn_mfma_f32_16x16x32_bf16(a[i], b[j], acc[i][j], 0, 0, 0);
    }
    __syncthreads();
  }
#pragma unroll
  for (int i = 0; i < 4; ++i)
#pragma unroll
    for (int j = 0; j < 4; ++j)
#pragma unroll
      for (int r = 0; r < 4; ++r) {
        int rowg = m0 + wm + 16 * i + grp * 4 + r;
        int colg = n0 + wn + 16 * j + row_l;
        float v = acc[i][j][r];
        if constexpr (sizeof(OUT) == 2) {
          C[(size_t)rowg * N + colg] = (OUT)f2b(v);
        } else {
          C[(size_t)rowg * N + colg] = v;
        }
      }
}

// ---------------- split qkv + RoPE(Q,K) ----------------
// qkv: [8192, 2304] bf16. Q,K: [B*H, S, 64] bf16 (Q pre-scaled 1/8).
__global__ __launch_bounds__(256) void split_rope_kernel(
    const unsigned short* __restrict__ qkv, const float2* __restrict__ tab,
    unsigned short* __restrict__ Qo, unsigned short* __restrict__ Ko) {
  int idx = blockIdx.x * 256 + threadIdx.x;  // (m, h, d2): 8192*12*32
  int d2 = idx & 31;
  int h = (idx >> 5) % 12;
  int m = idx / 384;
  int b = m >> 11, s = m & 2047;
  const unsigned short* rowp = qkv + (size_t)m * 2304;
  int c0 = h * 64 + 2 * d2;
  float qe = b2f(rowp[c0]),       qo = b2f(rowp[c0 + 1]);
  float ke = b2f(rowp[768 + c0]), ko = b2f(rowp[768 + c0 + 1]);
  float2 cs = tab[s * 32 + d2];
  float c = cs.x, sn = cs.y;
  float qre = (qe * c - qo * sn) * 0.125f;
  float qro = (qe * sn + qo * c) * 0.125f;
  float kre = ke * c - ko * sn;
  float kro = ke * sn + ko * c;
  size_t bh = (size_t)(b * 12 + h);
  size_t qoff = (bh * 2048 + s) * 64 + 2 * d2;
  ushort2 qv; qv.x = f2b(qre); qv.y = f2b(qro);
  *(ushort2*)&Qo[qoff] = qv;
  ushort2 kv; kv.x = f2b(kre); kv.y = f2b(kro);
  *(ushort2*)&Ko[qoff] = kv;
}

// ---------------- V transpose (LDS-tiled): Vt[bh][d][s] ----------------
__global__ __launch_bounds__(256) void vtrans_kernel(
    const unsigned short* __restrict__ qkv, unsigned short* __restrict__ Vt) {
  __shared__ unsigned short T[64][72];
  const int bh = blockIdx.x;   // 0..47
  const int st = blockIdx.y;   // 0..31
  const int b = bh / 12, h = bh - b * 12;
  const int t = threadIdx.x;
  const size_t m0 = (size_t)b * 2048 + st * 64;
  const int row = t >> 2;       // 0..63
  const int cp = t & 3;         // 16-col pack
  const unsigned short* src = qkv + (m0 + row) * 2304 + 1536 + h * 64 + cp * 16;
  *(bf16x8*)&T[row][cp * 16]     = *(const bf16x8*)src;
  *(bf16x8*)&T[row][cp * 16 + 8] = *(const bf16x8*)(src + 8);
  __syncthreads();
  const int d = t >> 2;         // 0..63
  const int sp = t & 3;         // 16-s pack
  unsigned short tmp[16];
#pragma unroll
  for (int i = 0; i < 16; ++i) tmp[i] = T[sp * 16 + i][d];
  unsigned short* dst = &Vt[((size_t)bh * 64 + d) * 2048 + st * 64 + sp * 16];
  *(bf16x8*)dst       = *(bf16x8*)&tmp[0];
  *(bf16x8*)(dst + 8) = *(bf16x8*)&tmp[8];
}

// ---------------- causal flash attention (swapped QK^T, 32x32 MFMA) --------
// grid (48, 16): x = b*12+h, y = 128-row q tile. 4 independent waves x 32 q.
__global__ __launch_bounds__(256) void attn_kernel(
    const unsigned short* __restrict__ Q, const unsigned short* __restrict__ Kc,
    const unsigned short* __restrict__ Vt, unsigned short* __restrict__ Ao) {
  __shared__ unsigned short Ol[4][32][72];
  const int lane = threadIdx.x & 63;
  const int wave = threadIdx.x >> 6;
  const int ql = lane & 31;   // q column (lane-local q row)
  const int hi = lane >> 5;
  const int bh = blockIdx.x;
  const int q0 = blockIdx.y * 128 + wave * 32;
  const size_t base = (size_t)bh * 2048 * 64;
  const size_t vbase = (size_t)bh * 64 * 2048;

  // Q as B-operand: lane holds Q[q0+ql][16*kk + hi*8 + j]
  bf16x8 bq[4];
  const unsigned short* qp = &Q[base + (size_t)(q0 + ql) * 64 + hi * 8];
#pragma unroll
  for (int kk = 0; kk < 4; ++kk) bq[kk] = *(const bf16x8*)(qp + kk * 16);

  f32x16 o0, o1;
#pragma unroll
  for (int i = 0; i < 16; ++i) { o0[i] = 0.f; o1[i] = 0.f; }
  float m = -3.0e38f, lsum = 0.f;

  const int nfull = q0 >> 5;
  for (int kt = 0; kt <= nfull; ++kt) {
    const int k0 = kt << 5;
    // ---- S^T = K * Q^T : lane holds S^T[k0+crow(r,hi)][q0+ql]
    f32x16 s;
#pragma unroll
    for (int i = 0; i < 16; ++i) s[i] = 0.f;
    const unsigned short* kp = &Kc[base + (size_t)(k0 + ql) * 64 + hi * 8];
#pragma unroll
    for (int kk = 0; kk < 4; ++kk) {
      bf16x8 ak = *(const bf16x8*)(kp + kk * 16);
      s = __builtin_amdgcn_mfma_f32_32x32x16_bf16(ak, bq[kk], s, 0, 0, 0);
    }
    if (kt == nfull) {  // diagonal: mask key > q
#pragma unroll
      for (int r = 0; r < 16; ++r) {
        int key = k0 + (r & 3) + ((r >> 2) << 3) + (hi << 2);
        if (key > q0 + ql) s[r] = -3.0e38f;
      }
    }
    // ---- online softmax (q is lane-local; reduce over 16 regs + pair lane^32)
    float tm = fmaxf(fmaxf(fmaxf(s[0], s[1]), fmaxf(s[2], s[3])),
                     fmaxf(fmaxf(s[4], s[5]), fmaxf(s[6], s[7])));
    tm = fmaxf(tm, fmaxf(fmaxf(fmaxf(s[8], s[9]), fmaxf(s[10], s[11])),
                         fmaxf(fmaxf(s[12], s[13]), fmaxf(s[14], s[15]))));
    tm = fmaxf(tm, __shfl_xor(tm, 32, 64));
    float nm = fmaxf(m, tm);
    float al = exp2f((m - nm) * L2E);
    m = nm;
    float mL2 = m * L2E;
    float p[16];
    float rs = 0.f;
#pragma unroll
    for (int r = 0; r < 16; ++r) {
      float pv = exp2f(s[r] * L2E - mL2);
      p[r] = pv;
      rs += pv;
    }
    lsum = lsum * al + rs;   // half-sum; pair-combined at the end
    o0 *= al;
    o1 *= al;
    // ---- P repack: cvt_pk pairs + permlane32_swap -> B-operand frags
    unsigned w0 = cvtpk(p[0], p[1]),   w2 = cvtpk(p[4], p[5]);
    unsigned w1 = cvtpk(p[2], p[3]),   w3 = cvtpk(p[6], p[7]);
    unsigned w4 = cvtpk(p[8], p[9]),   w6 = cvtpk(p[12], p[13]);
    unsigned w5 = cvtpk(p[10], p[11]), w7 = cvtpk(p[14], p[15]);
    plswap(w0, w2);  // -> words j0 and j2 of chunk ks=0
    plswap(w1, w3);  // -> words j1 and j3
    plswap(w4, w6);  // chunk ks=1
    plswap(w5, w7);
    union { unsigned u[4]; bf16x8 v; } pb0, pb1;
    pb0.u[0] = w0; pb0.u[1] = w1; pb0.u[2] = w2; pb0.u[3] = w3;
    pb1.u[0] = w4; pb1.u[1] = w5; pb1.u[2] = w6; pb1.u[3] = w7;
    // ---- O^T += V^T * P^T
    const unsigned short* vp0 = &Vt[vbase + (size_t)ql * 2048 + k0 + hi * 8];
    const unsigned short* vp1 = vp0 + (size_t)32 * 2048;
    bf16x8 av00 = *(const bf16x8*)vp0;
    bf16x8 av01 = *(const bf16x8*)(vp0 + 16);
    bf16x8 av10 = *(const bf16x8*)vp1;
    bf16x8 av11 = *(const bf16x8*)(vp1 + 16);
    o0 = __builtin_amdgcn_mfma_f32_32x32x16_bf16(av00, pb0.v, o0, 0, 0, 0);
    o0 = __builtin_amdgcn_mfma_f32_32x32x16_bf16(av01, pb1.v, o0, 0, 0, 0);
    o1 = __builtin_amdgcn_mfma_f32_32x32x16_bf16(av10, pb0.v, o1, 0, 0, 0);
    o1 = __builtin_amdgcn_mfma_f32_32x32x16_bf16(av11, pb1.v, o1, 0, 0, 0);
  }
  // ---- epilogue: normalize, transpose via LDS, coalesced store
  float lt = lsum + __shfl_xor(lsum, 32, 64);
  float linv = 1.0f / lt;
  unsigned short (*Ow)[72] = Ol[wave];
#pragma unroll
  for (int r = 0; r < 16; ++r) {
    int d = (r & 3) + ((r >> 2) << 3) + (hi << 2);
    Ow[ql][d]      = f2b(o0[r] * linv);
    Ow[ql][32 + d] = f2b(o1[r] * linv);
  }
  const int b = bh / 12, h = bh - b * 12;
  const int qr = lane >> 1, hf = lane & 1;
  unsigned short* orow = &Ao[((size_t)(b * 2048 + q0 + qr)) * 768 + h * 64 + hf * 32];
#pragma unroll
  for (int jj = 0; jj < 4; ++jj)
    *(bf16x8*)(orow + jj * 8) = *(bf16x8*)&Ow[qr][hf * 32 + jj * 8];
}

extern "C" void kernel_launch(void* const* d_in, const int* in_sizes, int n_in,
                              void* d_out, int out_size, void* d_ws, size_t ws_size,
                              hipStream_t stream) {
  const float* x  = (const float*)d_in[0];
  const float* wq = (const float*)d_in[1];
  const float* wk = (const float*)d_in[2];
  const float* wv = (const float*)d_in[3];
  const float* wo = (const float*)d_in[4];
  const int* tpos = (const int*)d_in[5];
  float* out = (float*)d_out;

  char* ws = (char*)d_ws;
  unsigned short* xb   = (unsigned short*)(ws + 0);           // 12,582,912 (reused as attn_out)
  unsigned short* wqkv = (unsigned short*)(ws + 12582912);    //  3,538,944
  unsigned short* wob  = (unsigned short*)(ws + 16121856);    //  1,179,648
  float2*         tab  = (float2*)(ws + 17301504);            //    524,288
  unsigned short* qkv  = (unsigned short*)(ws + 17825792);    // 37,748,736
  unsigned short* Qb   = (unsigned short*)(ws + 55574528);    // 12,582,912
  unsigned short* Kb   = (unsigned short*)(ws + 68157440);    // 12,582,912
  unsigned short* Vtb  = (unsigned short*)(ws + 80740352);    // 12,582,912
  unsigned short* aout = xb;  // alias: x_bf16 dead after GEMM1

  cvt_kernel<<<2048, 256, 0, stream>>>(x, xb, 8192 * 768 / 4);
  cvt_kernel<<<576, 256, 0, stream>>>(wq, wqkv, 768 * 768 / 4);
  cvt_kernel<<<576, 256, 0, stream>>>(wk, wqkv + 589824, 768 * 768 / 4);
  cvt_kernel<<<576, 256, 0, stream>>>(wv, wqkv + 1179648, 768 * 768 / 4);
  cvt_kernel<<<576, 256, 0, stream>>>(wo, wob, 768 * 768 / 4);
  rope_table_kernel<<<256, 256, 0, stream>>>(tpos, tab);
  gemm_nt<unsigned short><<<dim3(18, 64), 256, 0, stream>>>(xb, wqkv, qkv, 8192, 2304, 768);
  split_rope_kernel<<<12288, 256, 0, stream>>>(qkv, tab, Qb, Kb);
  vtrans_kernel<<<dim3(48, 32), 256, 0, stream>>>(qkv, Vtb);
  attn_kernel<<<dim3(48, 16), 256, 0, stream>>>(Qb, Kb, Vtb, aout);
  gemm_nt<float><<<dim3(6, 64), 256, 0, stream>>>(aout, wob, out, 8192, 768, 768);
}

// Round 7
// 296.408 us; speedup vs baseline: 1.4147x; 1.0739x over previous
//
#include <hip/hip_runtime.h>
#include <hip/hip_bf16.h>
#include <math.h>

#define L2E 1.44269504088896340736f

using f32x4  = __attribute__((ext_vector_type(4))) float;
using f32x16 = __attribute__((ext_vector_type(16))) float;
using bf16x8 = __attribute__((ext_vector_type(8))) short;

static __device__ __forceinline__ float b2f(unsigned short u) {
  union { unsigned u; float f; } v; v.u = ((unsigned)u) << 16; return v.f;
}
static __device__ __forceinline__ unsigned short f2b(float f) {
  union { float f; unsigned u; } v; v.f = f;
  unsigned r = (v.u + 0x7FFFu + ((v.u >> 16) & 1u)) >> 16;
  return (unsigned short)r;
}
static __device__ __forceinline__ unsigned cvtpk(float a, float b) {
  unsigned r;
  asm("v_cvt_pk_bf16_f32 %0, %1, %2" : "=v"(r) : "v"(a), "v"(b));
  return r;
}
static __device__ __forceinline__ void plswap(unsigned& a, unsigned& b) {
#if __has_builtin(__builtin_amdgcn_permlane32_swap)
  typedef unsigned u32x2 __attribute__((ext_vector_type(2)));
  u32x2 r = __builtin_amdgcn_permlane32_swap(a, b, false, false);
  a = r[0]; b = r[1];
#else
  unsigned as = (unsigned)__shfl_xor((int)a, 32, 64);
  unsigned bs = (unsigned)__shfl_xor((int)b, 32, 64);
  bool lo = (threadIdx.x & 32) == 0;
  unsigned na = lo ? a : bs;
  unsigned nb = lo ? as : b;
  a = na; b = nb;
#endif
}

// ---------------- fp32 -> bf16 convert (float4 vectorized) ----------------
__global__ void cvt_kernel(const float* __restrict__ src,
                           unsigned short* __restrict__ dst, int n4) {
  int i = blockIdx.x * blockDim.x + threadIdx.x;
  int stride = gridDim.x * blockDim.x;
  for (; i < n4; i += stride) {
    float4 v = ((const float4*)src)[i];
    ushort4 o;
    o.x = f2b(v.x); o.y = f2b(v.y); o.z = f2b(v.z); o.w = f2b(v.w);
    ((ushort4*)dst)[i] = o;
  }
}

// fused wq/wk/wv -> wqkv convert (each 589824 elems = 147456 float4)
__global__ void wcvt_kernel(const float* __restrict__ wq, const float* __restrict__ wk,
                            const float* __restrict__ wv, unsigned short* __restrict__ dst) {
  int i = blockIdx.x * blockDim.x + threadIdx.x;   // 0 .. 442367
  int which = i / 147456;
  int sub = i - which * 147456;
  const float* src = which == 0 ? wq : (which == 1 ? wk : wv);
  float4 v = ((const float4*)src)[sub];
  ushort4 o;
  o.x = f2b(v.x); o.y = f2b(v.y); o.z = f2b(v.z); o.w = f2b(v.w);
  ((ushort4*)dst)[i] = o;
}

// ---------------- RoPE cos/sin table ----------------
__global__ void rope_table_kernel(const int* __restrict__ pos,
                                  float2* __restrict__ tab) {
  int t = blockIdx.x * blockDim.x + threadIdx.x;   // 0..65535
  int s = t >> 5, j = t & 31;
  double p = (double)pos[s];
  double freq = pow(10000.0, -(double)(2 * j) / 64.0);
  double ang = p * freq;
  tab[t] = make_float2((float)cos(ang), (float)sin(ang));
}

// ---------------- NT GEMM: C[M,N] = A[M,K] * B[N,K]^T ----------------
template <typename OUT>
__global__ __launch_bounds__(256) void gemm_nt(const unsigned short* __restrict__ A,
                                               const unsigned short* __restrict__ B,
                                               OUT* __restrict__ C,
                                               int M, int N, int K) {
  __shared__ unsigned short As[128 * 64];
  __shared__ unsigned short Bs[128 * 64];
  const int t = threadIdx.x;
  const int lane = t & 63;
  const int row_l = lane & 15;
  const int grp = lane >> 4;
  const int wave = t >> 6;
  const int wm = (wave >> 1) * 64;
  const int wn = (wave & 1) * 64;
  const int m0 = blockIdx.y * 128;
  const int n0 = blockIdx.x * 128;

  f32x4 acc[4][4];
#pragma unroll
  for (int i = 0; i < 4; ++i)
#pragma unroll
    for (int j = 0; j < 4; ++j) acc[i][j] = (f32x4){0.f, 0.f, 0.f, 0.f};

  const int srow = t >> 3;
  const int scolb = (t & 7) * 16;
  const size_t lda = (size_t)K * 2;
  const char* Ab = (const char*)A + (size_t)m0 * lda + scolb;
  const char* Bb = (const char*)B + (size_t)n0 * lda + scolb;

  for (int k0 = 0; k0 < K; k0 += 64) {
#pragma unroll
    for (int it = 0; it < 4; ++it) {
      int row = it * 32 + srow;
      const char* ga = Ab + (size_t)row * lda + (size_t)k0 * 2;
      const char* gb = Bb + (size_t)row * lda + (size_t)k0 * 2;
      __builtin_amdgcn_global_load_lds(
          (const __attribute__((address_space(1))) unsigned*)ga,
          (__attribute__((address_space(3))) unsigned*)((char*)As + it * 4096 + t * 16),
          16, 0, 0);
      __builtin_amdgcn_global_load_lds(
          (const __attribute__((address_space(1))) unsigned*)gb,
          (__attribute__((address_space(3))) unsigned*)((char*)Bs + it * 4096 + t * 16),
          16, 0, 0);
    }
    __syncthreads();
#pragma unroll
    for (int kk = 0; kk < 2; ++kk) {
      bf16x8 a[4], b[4];
#pragma unroll
      for (int i = 0; i < 4; ++i)
        a[i] = *(const bf16x8*)&As[(wm + 16 * i + row_l) * 64 + kk * 32 + grp * 8];
#pragma unroll
      for (int j = 0; j < 4; ++j)
        b[j] = *(const bf16x8*)&Bs[(wn + 16 * j + row_l) * 64 + kk * 32 + grp * 8];
#pragma unroll
      for (int i = 0; i < 4; ++i)
#pragma unroll
        for (int j = 0; j < 4; ++j)
          acc[i][j] = __builtin_amdgcn_mfma_f32_16x16x32_bf16(a[i], b[j], acc[i][j], 0, 0, 0);
    }
    __syncthreads();
  }
#pragma unroll
  for (int i = 0; i < 4; ++i)
#pragma unroll
    for (int j = 0; j < 4; ++j)
#pragma unroll
      for (int r = 0; r < 4; ++r) {
        int rowg = m0 + wm + 16 * i + grp * 4 + r;
        int colg = n0 + wn + 16 * j + row_l;
        float v = acc[i][j][r];
        if constexpr (sizeof(OUT) == 2) {
          C[(size_t)rowg * N + colg] = (OUT)f2b(v);
        } else {
          C[(size_t)rowg * N + colg] = v;
        }
      }
}

// ---------------- split qkv + RoPE(Q,K) ----------------
__global__ __launch_bounds__(256) void split_rope_kernel(
    const unsigned short* __restrict__ qkv, const float2* __restrict__ tab,
    unsigned short* __restrict__ Qo, unsigned short* __restrict__ Ko) {
  int idx = blockIdx.x * 256 + threadIdx.x;  // (m, h, d2): 8192*12*32
  int d2 = idx & 31;
  int h = (idx >> 5) % 12;
  int m = idx / 384;
  int b = m >> 11, s = m & 2047;
  const unsigned short* rowp = qkv + (size_t)m * 2304;
  int c0 = h * 64 + 2 * d2;
  float qe = b2f(rowp[c0]),       qo = b2f(rowp[c0 + 1]);
  float ke = b2f(rowp[768 + c0]), ko = b2f(rowp[768 + c0 + 1]);
  float2 cs = tab[s * 32 + d2];
  float c = cs.x, sn = cs.y;
  float qre = (qe * c - qo * sn) * 0.125f;
  float qro = (qe * sn + qo * c) * 0.125f;
  float kre = ke * c - ko * sn;
  float kro = ke * sn + ko * c;
  size_t bh = (size_t)(b * 12 + h);
  size_t qoff = (bh * 2048 + s) * 64 + 2 * d2;
  ushort2 qv; qv.x = f2b(qre); qv.y = f2b(qro);
  *(ushort2*)&Qo[qoff] = qv;
  ushort2 kv; kv.x = f2b(kre); kv.y = f2b(kro);
  *(ushort2*)&Ko[qoff] = kv;
}

// ---------------- V transpose (LDS-tiled): Vt[bh][d][s] ----------------
__global__ __launch_bounds__(256) void vtrans_kernel(
    const unsigned short* __restrict__ qkv, unsigned short* __restrict__ Vt) {
  __shared__ unsigned short T[64][72];
  const int bh = blockIdx.x;   // 0..47
  const int st = blockIdx.y;   // 0..31
  const int b = bh / 12, h = bh - b * 12;
  const int t = threadIdx.x;
  const size_t m0 = (size_t)b * 2048 + st * 64;
  const int row = t >> 2;
  const int cp = t & 3;
  const unsigned short* src = qkv + (m0 + row) * 2304 + 1536 + h * 64 + cp * 16;
  *(bf16x8*)&T[row][cp * 16]     = *(const bf16x8*)src;
  *(bf16x8*)&T[row][cp * 16 + 8] = *(const bf16x8*)(src + 8);
  __syncthreads();
  const int d = t >> 2;
  const int sp = t & 3;
  unsigned short tmp[16];
#pragma unroll
  for (int i = 0; i < 16; ++i) tmp[i] = T[sp * 16 + i][d];
  unsigned short* dst = &Vt[((size_t)bh * 64 + d) * 2048 + st * 64 + sp * 16];
  *(bf16x8*)dst       = *(bf16x8*)&tmp[0];
  *(bf16x8*)(dst + 8) = *(bf16x8*)&tmp[8];
}

// ---------------- causal flash attention, split-KV x4 + LDS merge ----------
// grid (48, 64): x = b*12+h, y -> p = 63-y (heavy-first), q0 = p*32.
// Wave w handles key tiles kt = w, w+4, ... <= p with private (m,l,O);
// merged across waves in LDS at the end.
__global__ __launch_bounds__(256) void attn_kernel(
    const unsigned short* __restrict__ Q, const unsigned short* __restrict__ Kc,
    const unsigned short* __restrict__ Vt, unsigned short* __restrict__ Ao) {
  __shared__ float Ob[4][32][68];   // padded: 4-way max bank aliasing on scatter
  __shared__ float Ml[4][32];
  __shared__ float Ll[4][32];
  const int lane = threadIdx.x & 63;
  const int wave = threadIdx.x >> 6;
  const int ql = lane & 31;
  const int hi = lane >> 5;
  const int bh = blockIdx.x;
  const int p = (int)gridDim.y - 1 - (int)blockIdx.y;  // heavy chunks first
  const int q0 = p << 5;
  const size_t base = (size_t)bh * 2048 * 64;

  // Q as B-operand: lane holds Q[q0+ql][16*kk + hi*8 + j]
  bf16x8 bq[4];
  const unsigned short* qp = &Q[base + (size_t)(q0 + ql) * 64 + hi * 8];
#pragma unroll
  for (int kk = 0; kk < 4; ++kk) bq[kk] = *(const bf16x8*)(qp + kk * 16);

  f32x16 o0, o1;
#pragma unroll
  for (int i = 0; i < 16; ++i) { o0[i] = 0.f; o1[i] = 0.f; }
  float m = -3.0e38f, lsum = 0.f;

  for (int kt = wave; kt <= p; kt += 4) {
    const int k0 = kt << 5;
    // S^T = K * Q^T : lane holds S^T[k0+crow(r,hi)][q0+ql]
    f32x16 s;
#pragma unroll
    for (int i = 0; i < 16; ++i) s[i] = 0.f;
    const unsigned short* kp = &Kc[base + (size_t)(k0 + ql) * 64 + hi * 8];
#pragma unroll
    for (int kk = 0; kk < 4; ++kk) {
      bf16x8 ak = *(const bf16x8*)(kp + kk * 16);
      s = __builtin_amdgcn_mfma_f32_32x32x16_bf16(ak, bq[kk], s, 0, 0, 0);
    }
    if (kt == p) {  // diagonal: mask key > q
#pragma unroll
      for (int r = 0; r < 16; ++r) {
        int key = k0 + (r & 3) + ((r >> 2) << 3) + (hi << 2);
        if (key > q0 + ql) s[r] = -3.0e38f;
      }
    }
    // online softmax (q lane-local; reduce 16 regs + pair lane^32)
    float tm = fmaxf(fmaxf(fmaxf(s[0], s[1]), fmaxf(s[2], s[3])),
                     fmaxf(fmaxf(s[4], s[5]), fmaxf(s[6], s[7])));
    tm = fmaxf(tm, fmaxf(fmaxf(fmaxf(s[8], s[9]), fmaxf(s[10], s[11])),
                         fmaxf(fmaxf(s[12], s[13]), fmaxf(s[14], s[15]))));
    tm = fmaxf(tm, __shfl_xor(tm, 32, 64));
    float nm = fmaxf(m, tm);
    float al = exp2f((m - nm) * L2E);
    m = nm;
    float mL2 = m * L2E;
    float pr[16];
    float rs = 0.f;
#pragma unroll
    for (int r = 0; r < 16; ++r) {
      float pv = exp2f(s[r] * L2E - mL2);
      pr[r] = pv;
      rs += pv;
    }
    lsum = lsum * al + rs;
    o0 *= al;
    o1 *= al;
    // P repack: cvt_pk + permlane32_swap -> B-operand frags
    unsigned w0 = cvtpk(pr[0], pr[1]),   w2 = cvtpk(pr[4], pr[5]);
    unsigned w1 = cvtpk(pr[2], pr[3]),   w3 = cvtpk(pr[6], pr[7]);
    unsigned w4 = cvtpk(pr[8], pr[9]),   w6 = cvtpk(pr[12], pr[13]);
    unsigned w5 = cvtpk(pr[10], pr[11]), w7 = cvtpk(pr[14], pr[15]);
    plswap(w0, w2);
    plswap(w1, w3);
    plswap(w4, w6);
    plswap(w5, w7);
    union { unsigned u[4]; bf16x8 v; } pb0, pb1;
    pb0.u[0] = w0; pb0.u[1] = w1; pb0.u[2] = w2; pb0.u[3] = w3;
    pb1.u[0] = w4; pb1.u[1] = w5; pb1.u[2] = w6; pb1.u[3] = w7;
    // O^T += V^T * P^T
    const unsigned short* vp0 = &Vt[base + (size_t)ql * 2048 + k0 + hi * 8];
    const unsigned short* vp1 = vp0 + (size_t)32 * 2048;
    bf16x8 av00 = *(const bf16x8*)vp0;
    bf16x8 av01 = *(const bf16x8*)(vp0 + 16);
    bf16x8 av10 = *(const bf16x8*)vp1;
    bf16x8 av11 = *(const bf16x8*)(vp1 + 16);
    o0 = __builtin_amdgcn_mfma_f32_32x32x16_bf16(av00, pb0.v, o0, 0, 0, 0);
    o0 = __builtin_amdgcn_mfma_f32_32x32x16_bf16(av01, pb1.v, o0, 0, 0, 0);
    o1 = __builtin_amdgcn_mfma_f32_32x32x16_bf16(av10, pb0.v, o1, 0, 0, 0);
    o1 = __builtin_amdgcn_mfma_f32_32x32x16_bf16(av11, pb1.v, o1, 0, 0, 0);
  }
  // ---- write per-wave partials
  float lt = lsum + __shfl_xor(lsum, 32, 64);   // combine hi halves
  if (hi == 0) { Ml[wave][ql] = m; Ll[wave][ql] = lt; }
#pragma unroll
  for (int r = 0; r < 16; ++r) {
    int d = (r & 3) + ((r >> 2) << 3) + (hi << 2);
    Ob[wave][ql][d]      = o0[r];
    Ob[wave][ql][32 + d] = o1[r];
  }
  __syncthreads();
  // ---- merge: wave handles q rows wave*8..wave*8+7; lane = (qrow, d-block)
  const int qr = (wave << 3) + (lane >> 3);
  const int db = (lane & 7) << 3;
  float m0 = Ml[0][qr], m1 = Ml[1][qr], m2 = Ml[2][qr], m3 = Ml[3][qr];
  float ms = fmaxf(fmaxf(m0, m1), fmaxf(m2, m3));
  float sc0 = exp2f((m0 - ms) * L2E);
  float sc1 = exp2f((m1 - ms) * L2E);
  float sc2 = exp2f((m2 - ms) * L2E);
  float sc3 = exp2f((m3 - ms) * L2E);
  float lstar = sc0 * Ll[0][qr] + sc1 * Ll[1][qr] + sc2 * Ll[2][qr] + sc3 * Ll[3][qr];
  float linv = 1.0f / lstar;
  unsigned short ov[8];
#pragma unroll
  for (int j = 0; j < 8; ++j) {
    float a = sc0 * Ob[0][qr][db + j] + sc1 * Ob[1][qr][db + j]
            + sc2 * Ob[2][qr][db + j] + sc3 * Ob[3][qr][db + j];
    ov[j] = f2b(a * linv);
  }
  const int b = bh / 12, h = bh - b * 12;
  *(bf16x8*)&Ao[((size_t)(b * 2048 + q0 + qr)) * 768 + h * 64 + db] = *(bf16x8*)ov;
}

extern "C" void kernel_launch(void* const* d_in, const int* in_sizes, int n_in,
                              void* d_out, int out_size, void* d_ws, size_t ws_size,
                              hipStream_t stream) {
  const float* x  = (const float*)d_in[0];
  const float* wq = (const float*)d_in[1];
  const float* wk = (const float*)d_in[2];
  const float* wv = (const float*)d_in[3];
  const float* wo = (const float*)d_in[4];
  const int* tpos = (const int*)d_in[5];
  float* out = (float*)d_out;

  char* ws = (char*)d_ws;
  unsigned short* xb   = (unsigned short*)(ws + 0);           // 12,582,912 (reused as attn_out)
  unsigned short* wqkv = (unsigned short*)(ws + 12582912);    //  3,538,944
  unsigned short* wob  = (unsigned short*)(ws + 16121856);    //  1,179,648
  float2*         tab  = (float2*)(ws + 17301504);            //    524,288
  unsigned short* qkv  = (unsigned short*)(ws + 17825792);    // 37,748,736
  unsigned short* Qb   = (unsigned short*)(ws + 55574528);    // 12,582,912
  unsigned short* Kb   = (unsigned short*)(ws + 68157440);    // 12,582,912
  unsigned short* Vtb  = (unsigned short*)(ws + 80740352);    // 12,582,912
  unsigned short* aout = xb;  // alias: x_bf16 dead after GEMM1

  cvt_kernel<<<2048, 256, 0, stream>>>(x, xb, 8192 * 768 / 4);
  wcvt_kernel<<<1728, 256, 0, stream>>>(wq, wk, wv, wqkv);
  cvt_kernel<<<576, 256, 0, stream>>>(wo, wob, 768 * 768 / 4);
  rope_table_kernel<<<256, 256, 0, stream>>>(tpos, tab);
  gemm_nt<unsigned short><<<dim3(18, 64), 256, 0, stream>>>(xb, wqkv, qkv, 8192, 2304, 768);
  split_rope_kernel<<<12288, 256, 0, stream>>>(qkv, tab, Qb, Kb);
  vtrans_kernel<<<dim3(48, 32), 256, 0, stream>>>(qkv, Vtb);
  attn_kernel<<<dim3(48, 64), 256, 0, stream>>>(Qb, Kb, Vtb, aout);
  gemm_nt<float><<<dim3(6, 64), 256, 0, stream>>>(aout, wob, out, 8192, 768, 768);
}

// Round 10
// 293.128 us; speedup vs baseline: 1.4305x; 1.0112x over previous
//
#include <hip/hip_runtime.h>
#include <hip/hip_bf16.h>
#include <math.h>

#define L2E 1.44269504088896340736f

using f32x4  = __attribute__((ext_vector_type(4))) float;
using f32x16 = __attribute__((ext_vector_type(16))) float;
using bf16x8 = __attribute__((ext_vector_type(8))) short;

static __device__ __forceinline__ float b2f(unsigned short u) {
  union { unsigned u; float f; } v; v.u = ((unsigned)u) << 16; return v.f;
}
static __device__ __forceinline__ unsigned short f2b(float f) {
  union { float f; unsigned u; } v; v.f = f;
  unsigned r = (v.u + 0x7FFFu + ((v.u >> 16) & 1u)) >> 16;
  return (unsigned short)r;
}
static __device__ __forceinline__ unsigned cvtpk(float a, float b) {
  unsigned r;
  asm("v_cvt_pk_bf16_f32 %0, %1, %2" : "=v"(r) : "v"(a), "v"(b));
  return r;
}
static __device__ __forceinline__ void plswap(unsigned& a, unsigned& b) {
#if __has_builtin(__builtin_amdgcn_permlane32_swap)
  typedef unsigned u32x2 __attribute__((ext_vector_type(2)));
  u32x2 r = __builtin_amdgcn_permlane32_swap(a, b, false, false);
  a = r[0]; b = r[1];
#else
  unsigned as = (unsigned)__shfl_xor((int)a, 32, 64);
  unsigned bs = (unsigned)__shfl_xor((int)b, 32, 64);
  bool lo = (threadIdx.x & 32) == 0;
  unsigned na = lo ? a : bs;
  unsigned nb = lo ? as : b;
  a = na; b = nb;
#endif
}

// ---------------- fp32 -> bf16 convert (float4 vectorized) ----------------
__global__ void cvt_kernel(const float* __restrict__ src,
                           unsigned short* __restrict__ dst, int n4) {
  int i = blockIdx.x * blockDim.x + threadIdx.x;
  int stride = gridDim.x * blockDim.x;
  for (; i < n4; i += stride) {
    float4 v = ((const float4*)src)[i];
    ushort4 o;
    o.x = f2b(v.x); o.y = f2b(v.y); o.z = f2b(v.z); o.w = f2b(v.w);
    ((ushort4*)dst)[i] = o;
  }
}

// fused wq/wk/wv -> wqkv convert
__global__ void wcvt_kernel(const float* __restrict__ wq, const float* __restrict__ wk,
                            const float* __restrict__ wv, unsigned short* __restrict__ dst) {
  int i = blockIdx.x * blockDim.x + threadIdx.x;   // 0 .. 442367
  int which = i / 147456;
  int sub = i - which * 147456;
  const float* src = which == 0 ? wq : (which == 1 ? wk : wv);
  float4 v = ((const float4*)src)[sub];
  ushort4 o;
  o.x = f2b(v.x); o.y = f2b(v.y); o.z = f2b(v.z); o.w = f2b(v.w);
  ((ushort4*)dst)[i] = o;
}

// ---------------- RoPE cos/sin table ----------------
__global__ void rope_table_kernel(const int* __restrict__ pos,
                                  float2* __restrict__ tab) {
  int t = blockIdx.x * blockDim.x + threadIdx.x;   // 0..65535
  int s = t >> 5, j = t & 31;
  double p = (double)pos[s];
  double freq = pow(10000.0, -(double)(2 * j) / 64.0);
  double ang = p * freq;
  tab[t] = make_float2((float)cos(ang), (float)sin(ang));
}

// ---------------- NT GEMM: C[M,N] = A[M,K] * B[N,K]^T ----------------
template <typename OUT>
__global__ __launch_bounds__(256) void gemm_nt(const unsigned short* __restrict__ A,
                                               const unsigned short* __restrict__ B,
                                               OUT* __restrict__ C,
                                               int M, int N, int K) {
  __shared__ unsigned short As[128 * 64];
  __shared__ unsigned short Bs[128 * 64];
  const int t = threadIdx.x;
  const int lane = t & 63;
  const int row_l = lane & 15;
  const int grp = lane >> 4;
  const int wave = t >> 6;
  const int wm = (wave >> 1) * 64;
  const int wn = (wave & 1) * 64;
  const int m0 = blockIdx.y * 128;
  const int n0 = blockIdx.x * 128;

  f32x4 acc[4][4];
#pragma unroll
  for (int i = 0; i < 4; ++i)
#pragma unroll
    for (int j = 0; j < 4; ++j) acc[i][j] = (f32x4){0.f, 0.f, 0.f, 0.f};

  const int srow = t >> 3;
  const int scolb = (t & 7) * 16;
  const size_t lda = (size_t)K * 2;
  const char* Ab = (const char*)A + (size_t)m0 * lda + scolb;
  const char* Bb = (const char*)B + (size_t)n0 * lda + scolb;

  for (int k0 = 0; k0 < K; k0 += 64) {
#pragma unroll
    for (int it = 0; it < 4; ++it) {
      int row = it * 32 + srow;
      const char* ga = Ab + (size_t)row * lda + (size_t)k0 * 2;
      const char* gb = Bb + (size_t)row * lda + (size_t)k0 * 2;
      __builtin_amdgcn_global_load_lds(
          (const __attribute__((address_space(1))) unsigned*)ga,
          (__attribute__((address_space(3))) unsigned*)((char*)As + it * 4096 + t * 16),
          16, 0, 0);
      __builtin_amdgcn_global_load_lds(
          (const __attribute__((address_space(1))) unsigned*)gb,
          (__attribute__((address_space(3))) unsigned*)((char*)Bs + it * 4096 + t * 16),
          16, 0, 0);
    }
    __syncthreads();
#pragma unroll
    for (int kk = 0; kk < 2; ++kk) {
      bf16x8 a[4], b[4];
#pragma unroll
      for (int i = 0; i < 4; ++i)
        a[i] = *(const bf16x8*)&As[(wm + 16 * i + row_l) * 64 + kk * 32 + grp * 8];
#pragma unroll
      for (int j = 0; j < 4; ++j)
        b[j] = *(const bf16x8*)&Bs[(wn + 16 * j + row_l) * 64 + kk * 32 + grp * 8];
#pragma unroll
      for (int i = 0; i < 4; ++i)
#pragma unroll
        for (int j = 0; j < 4; ++j)
          acc[i][j] = __builtin_amdgcn_mfma_f32_16x16x32_bf16(a[i], b[j], acc[i][j], 0, 0, 0);
    }
    __syncthreads();
  }
#pragma unroll
  for (int i = 0; i < 4; ++i)
#pragma unroll
    for (int j = 0; j < 4; ++j)
#pragma unroll
      for (int r = 0; r < 4; ++r) {
        int rowg = m0 + wm + 16 * i + grp * 4 + r;
        int colg = n0 + wn + 16 * j + row_l;
        float v = acc[i][j][r];
        if constexpr (sizeof(OUT) == 2) {
          C[(size_t)rowg * N + colg] = (OUT)f2b(v);
        } else {
          C[(size_t)rowg * N + colg] = v;
        }
      }
}

// ---------------- split qkv + RoPE(Q,K) ----------------
__global__ __launch_bounds__(256) void split_rope_kernel(
    const unsigned short* __restrict__ qkv, const float2* __restrict__ tab,
    unsigned short* __restrict__ Qo, unsigned short* __restrict__ Ko) {
  int idx = blockIdx.x * 256 + threadIdx.x;  // (m, h, d2): 8192*12*32
  int d2 = idx & 31;
  int h = (idx >> 5) % 12;
  int m = idx / 384;
  int b = m >> 11, s = m & 2047;
  const unsigned short* rowp = qkv + (size_t)m * 2304;
  int c0 = h * 64 + 2 * d2;
  float qe = b2f(rowp[c0]),       qo = b2f(rowp[c0 + 1]);
  float ke = b2f(rowp[768 + c0]), ko = b2f(rowp[768 + c0 + 1]);
  float2 cs = tab[s * 32 + d2];
  float c = cs.x, sn = cs.y;
  float qre = (qe * c - qo * sn) * 0.125f;
  float qro = (qe * sn + qo * c) * 0.125f;
  float kre = ke * c - ko * sn;
  float kro = ke * sn + ko * c;
  size_t bh = (size_t)(b * 12 + h);
  size_t qoff = (bh * 2048 + s) * 64 + 2 * d2;
  ushort2 qv; qv.x = f2b(qre); qv.y = f2b(qro);
  *(ushort2*)&Qo[qoff] = qv;
  ushort2 kv; kv.x = f2b(kre); kv.y = f2b(kro);
  *(ushort2*)&Ko[qoff] = kv;
}

// ---------------- V transpose (LDS-tiled): Vt[bh][d][s] ----------------
__global__ __launch_bounds__(256) void vtrans_kernel(
    const unsigned short* __restrict__ qkv, unsigned short* __restrict__ Vt) {
  __shared__ unsigned short T[64][72];
  const int bh = blockIdx.x;   // 0..47
  const int st = blockIdx.y;   // 0..31
  const int b = bh / 12, h = bh - b * 12;
  const int t = threadIdx.x;
  const size_t m0 = (size_t)b * 2048 + st * 64;
  const int row = t >> 2;
  const int cp = t & 3;
  const unsigned short* src = qkv + (m0 + row) * 2304 + 1536 + h * 64 + cp * 16;
  *(bf16x8*)&T[row][cp * 16]     = *(const bf16x8*)src;
  *(bf16x8*)&T[row][cp * 16 + 8] = *(const bf16x8*)(src + 8);
  __syncthreads();
  const int d = t >> 2;
  const int sp = t & 3;
  unsigned short tmp[16];
#pragma unroll
  for (int i = 0; i < 16; ++i) tmp[i] = T[sp * 16 + i][d];
  unsigned short* dst = &Vt[((size_t)bh * 64 + d) * 2048 + st * 64 + sp * 16];
  *(bf16x8*)dst       = *(bf16x8*)&tmp[0];
  *(bf16x8*)(dst + 8) = *(bf16x8*)&tmp[8];
}

// ---------------- causal flash attention, split-KV x4, 64-key tiles -------
// grid (48, 64): x = b*12+h, y -> p = 63-y (heavy-first), q0 = p*32.
// Wave w handles 64-key tiles t = w, w+4, ...; remainder tile (incl diagonal)
// goes to wave (nfull&3). Private (m,l,O) per wave, LDS-merged at the end.
// Defer-max: skip O-rescale while tile max <= m+8 (P bounded by e^8).
__global__ __launch_bounds__(256, 4) void attn_kernel(
    const unsigned short* __restrict__ Q, const unsigned short* __restrict__ Kc,
    const unsigned short* __restrict__ Vt, unsigned short* __restrict__ Ao) {
  __shared__ float Ob[4][32][68];
  __shared__ float Ml[4][32];
  __shared__ float Ll[4][32];
  const int lane = threadIdx.x & 63;
  const int wave = threadIdx.x >> 6;
  const int ql = lane & 31;
  const int hi = lane >> 5;
  const int bh = blockIdx.x;
  const int p = (int)gridDim.y - 1 - (int)blockIdx.y;  // heavy chunks first
  const int q0 = p << 5;
  const size_t base = (size_t)bh * 2048 * 64;

  bf16x8 bq[4];
  const unsigned short* qp = &Q[base + (size_t)(q0 + ql) * 64 + hi * 8];
#pragma unroll
  for (int kk = 0; kk < 4; ++kk) bq[kk] = *(const bf16x8*)(qp + kk * 16);

  f32x16 o0, o1;
#pragma unroll
  for (int i = 0; i < 16; ++i) { o0[i] = 0.f; o1[i] = 0.f; }
  float m = -3.0e38f, lsum = 0.f;

  const unsigned short* kbase  = &Kc[base + (size_t)ql * 64 + hi * 8];
  const unsigned short* vbase0 = &Vt[base + (size_t)ql * 2048 + hi * 8];
  const unsigned short* vbase1 = vbase0 + (size_t)32 * 2048;
  const int nfull = q0 >> 6;   // full (unmasked) 64-key tiles

#define BODY64(K0, DOMASK)                                                     \
  {                                                                            \
    const int k0_ = (K0);                                                      \
    const unsigned short* kp = kbase + (size_t)k0_ * 64;                       \
    bf16x8 ak[4];                                                              \
    f32x16 slo, shi;                                                           \
    _Pragma("unroll") for (int i = 0; i < 16; ++i) { slo[i] = 0.f; shi[i] = 0.f; } \
    _Pragma("unroll") for (int kk = 0; kk < 4; ++kk)                           \
        ak[kk] = *(const bf16x8*)(kp + kk * 16);                               \
    _Pragma("unroll") for (int kk = 0; kk < 4; ++kk)                           \
        slo = __builtin_amdgcn_mfma_f32_32x32x16_bf16(ak[kk], bq[kk], slo, 0, 0, 0); \
    _Pragma("unroll") for (int kk = 0; kk < 4; ++kk)                           \
        ak[kk] = *(const bf16x8*)(kp + 32 * 64 + kk * 16);                     \
    /* early V loads for o0 half (hide under softmax) */                       \
    const unsigned short* vp0 = vbase0 + k0_;                                  \
    bf16x8 av0[4];                                                             \
    _Pragma("unroll") for (int c = 0; c < 4; ++c)                              \
        av0[c] = *(const bf16x8*)(vp0 + c * 16);                               \
    _Pragma("unroll") for (int kk = 0; kk < 4; ++kk)                           \
        shi = __builtin_amdgcn_mfma_f32_32x32x16_bf16(ak[kk], bq[kk], shi, 0, 0, 0); \
    if (DOMASK) {                                                              \
      _Pragma("unroll") for (int r = 0; r < 16; ++r) {                         \
        int key = k0_ + (r & 3) + ((r >> 2) << 3) + (hi << 2);                 \
        if (key > q0 + ql)      slo[r] = -3.0e38f;                             \
        if (key + 32 > q0 + ql) shi[r] = -3.0e38f;                             \
      }                                                                        \
    }                                                                          \
    float t0 = fmaxf(fmaxf(fmaxf(slo[0], slo[1]), fmaxf(slo[2], slo[3])),     \
                     fmaxf(fmaxf(slo[4], slo[5]), fmaxf(slo[6], slo[7])));    \
    float t1 = fmaxf(fmaxf(fmaxf(slo[8], slo[9]), fmaxf(slo[10], slo[11])),   \
                     fmaxf(fmaxf(slo[12], slo[13]), fmaxf(slo[14], slo[15]))); \
    float t2 = fmaxf(fmaxf(fmaxf(shi[0], shi[1]), fmaxf(shi[2], shi[3])),     \
                     fmaxf(fmaxf(shi[4], shi[5]), fmaxf(shi[6], shi[7])));    \
    float t3 = fmaxf(fmaxf(fmaxf(shi[8], shi[9]), fmaxf(shi[10], shi[11])),   \
                     fmaxf(fmaxf(shi[12], shi[13]), fmaxf(shi[14], shi[15]))); \
    float tm = fmaxf(fmaxf(t0, t1), fmaxf(t2, t3));                            \
    tm = fmaxf(tm, __shfl_xor(tm, 32, 64));                                    \
    if (!__all(tm <= m + 8.0f)) {                                              \
      float nm = fmaxf(m, tm);                                                 \
      float al = exp2f((m - nm) * L2E);                                        \
      m = nm;                                                                  \
      lsum *= al;                                                              \
      o0 *= al;                                                                \
      o1 *= al;                                                                \
    }                                                                          \
    float mL2 = m * L2E;                                                       \
    float rs = 0.f;                                                            \
    _Pragma("unroll") for (int r = 0; r < 16; ++r) {                           \
      slo[r] = exp2f(slo[r] * L2E - mL2); rs += slo[r];                        \
    }                                                                          \
    _Pragma("unroll") for (int r = 0; r < 16; ++r) {                           \
      shi[r] = exp2f(shi[r] * L2E - mL2); rs += shi[r];                        \
    }                                                                          \
    lsum += rs;                                                                \
    unsigned w0 = cvtpk(slo[0], slo[1]),   w2 = cvtpk(slo[4], slo[5]);         \
    unsigned w1 = cvtpk(slo[2], slo[3]),   w3 = cvtpk(slo[6], slo[7]);         \
    unsigned w4 = cvtpk(slo[8], slo[9]),   w6 = cvtpk(slo[12], slo[13]);       \
    unsigned w5 = cvtpk(slo[10], slo[11]), w7 = cvtpk(slo[14], slo[15]);       \
    plswap(w0, w2); plswap(w1, w3); plswap(w4, w6); plswap(w5, w7);            \
    union { unsigned u[4]; bf16x8 v; } pb0, pb1, pb2, pb3;                     \
    pb0.u[0] = w0; pb0.u[1] = w1; pb0.u[2] = w2; pb0.u[3] = w3;                \
    pb1.u[0] = w4; pb1.u[1] = w5; pb1.u[2] = w6; pb1.u[3] = w7;                \
    unsigned x0 = cvtpk(shi[0], shi[1]),   x2 = cvtpk(shi[4], shi[5]);         \
    unsigned x1 = cvtpk(shi[2], shi[3]),   x3 = cvtpk(shi[6], shi[7]);         \
    unsigned x4 = cvtpk(shi[8], shi[9]),   x6 = cvtpk(shi[12], shi[13]);       \
    unsigned x5 = cvtpk(shi[10], shi[11]), x7 = cvtpk(shi[14], shi[15]);       \
    plswap(x0, x2); plswap(x1, x3); plswap(x4, x6); plswap(x5, x7);            \
    pb2.u[0] = x0; pb2.u[1] = x1; pb2.u[2] = x2; pb2.u[3] = x3;                \
    pb3.u[0] = x4; pb3.u[1] = x5; pb3.u[2] = x6; pb3.u[3] = x7;                \
    const unsigned short* vp1 = vbase1 + k0_;                                  \
    bf16x8 av1[4];                                                             \
    _Pragma("unroll") for (int c = 0; c < 4; ++c)                              \
        av1[c] = *(const bf16x8*)(vp1 + c * 16);                               \
    o0 = __builtin_amdgcn_mfma_f32_32x32x16_bf16(av0[0], pb0.v, o0, 0, 0, 0);  \
    o0 = __builtin_amdgcn_mfma_f32_32x32x16_bf16(av0[1], pb1.v, o0, 0, 0, 0);  \
    o0 = __builtin_amdgcn_mfma_f32_32x32x16_bf16(av0[2], pb2.v, o0, 0, 0, 0);  \
    o0 = __builtin_amdgcn_mfma_f32_32x32x16_bf16(av0[3], pb3.v, o0, 0, 0, 0);  \
    o1 = __builtin_amdgcn_mfma_f32_32x32x16_bf16(av1[0], pb0.v, o1, 0, 0, 0);  \
    o1 = __builtin_amdgcn_mfma_f32_32x32x16_bf16(av1[1], pb1.v, o1, 0, 0, 0);  \
    o1 = __builtin_amdgcn_mfma_f32_32x32x16_bf16(av1[2], pb2.v, o1, 0, 0, 0);  \
    o1 = __builtin_amdgcn_mfma_f32_32x32x16_bf16(av1[3], pb3.v, o1, 0, 0, 0);  \
  }

  for (int t = wave; t < nfull; t += 4) BODY64(t << 6, false)
  if (wave == (nfull & 3)) BODY64(nfull << 6, true)
#undef BODY64

  // ---- write per-wave partials
  float lt = lsum + __shfl_xor(lsum, 32, 64);
  if (hi == 0) { Ml[wave][ql] = m; Ll[wave][ql] = lt; }
#pragma unroll
  for (int r = 0; r < 16; ++r) {
    int d = (r & 3) + ((r >> 2) << 3) + (hi << 2);
    Ob[wave][ql][d]      = o0[r];
    Ob[wave][ql][32 + d] = o1[r];
  }
  __syncthreads();
  // ---- merge
  const int qr = (wave << 3) + (lane >> 3);
  const int db = (lane & 7) << 3;
  float m0 = Ml[0][qr], m1 = Ml[1][qr], m2 = Ml[2][qr], m3 = Ml[3][qr];
  float ms = fmaxf(fmaxf(m0, m1), fmaxf(m2, m3));
  float sc0 = exp2f((m0 - ms) * L2E);
  float sc1 = exp2f((m1 - ms) * L2E);
  float sc2 = exp2f((m2 - ms) * L2E);
  float sc3 = exp2f((m3 - ms) * L2E);
  float lstar = sc0 * Ll[0][qr] + sc1 * Ll[1][qr] + sc2 * Ll[2][qr] + sc3 * Ll[3][qr];
  float linv = 1.0f / lstar;
  unsigned short ov[8];
#pragma unroll
  for (int j = 0; j < 8; ++j) {
    float a = sc0 * Ob[0][qr][db + j] + sc1 * Ob[1][qr][db + j]
            + sc2 * Ob[2][qr][db + j] + sc3 * Ob[3][qr][db + j];
    ov[j] = f2b(a * linv);
  }
  const int b = bh / 12, h = bh - b * 12;
  *(bf16x8*)&Ao[((size_t)(b * 2048 + q0 + qr)) * 768 + h * 64 + db] = *(bf16x8*)ov;
}

extern "C" void kernel_launch(void* const* d_in, const int* in_sizes, int n_in,
                              void* d_out, int out_size, void* d_ws, size_t ws_size,
                              hipStream_t stream) {
  const float* x  = (const float*)d_in[0];
  const float* wq = (const float*)d_in[1];
  const float* wk = (const float*)d_in[2];
  const float* wv = (const float*)d_in[3];
  const float* wo = (const float*)d_in[4];
  const int* tpos = (const int*)d_in[5];
  float* out = (float*)d_out;

  char* ws = (char*)d_ws;
  unsigned short* xb   = (unsigned short*)(ws + 0);           // 12,582,912 (reused as attn_out)
  unsigned short* wqkv = (unsigned short*)(ws + 12582912);    //  3,538,944
  unsigned short* wob  = (unsigned short*)(ws + 16121856);    //  1,179,648
  float2*         tab  = (float2*)(ws + 17301504);            //    524,288
  unsigned short* qkv  = (unsigned short*)(ws + 17825792);    // 37,748,736
  unsigned short* Qb   = (unsigned short*)(ws + 55574528);    // 12,582,912
  unsigned short* Kb   = (unsigned short*)(ws + 68157440);    // 12,582,912
  unsigned short* Vtb  = (unsigned short*)(ws + 80740352);    // 12,582,912
  unsigned short* aout = xb;  // alias: x_bf16 dead after GEMM1

  cvt_kernel<<<2048, 256, 0, stream>>>(x, xb, 8192 * 768 / 4);
  wcvt_kernel<<<1728, 256, 0, stream>>>(wq, wk, wv, wqkv);
  cvt_kernel<<<576, 256, 0, stream>>>(wo, wob, 768 * 768 / 4);
  rope_table_kernel<<<256, 256, 0, stream>>>(tpos, tab);
  gemm_nt<unsigned short><<<dim3(18, 64), 256, 0, stream>>>(xb, wqkv, qkv, 8192, 2304, 768);
  split_rope_kernel<<<12288, 256, 0, stream>>>(qkv, tab, Qb, Kb);
  vtrans_kernel<<<dim3(48, 32), 256, 0, stream>>>(qkv, Vtb);
  attn_kernel<<<dim3(48, 64), 256, 0, stream>>>(Qb, Kb, Vtb, aout);
  gemm_nt<float><<<dim3(6, 64), 256, 0, stream>>>(aout, wob, out, 8192, 768, 768);
}